// Round 14
// baseline (331.373 us; speedup 1.0000x reference)
//
#include <hip/hip_runtime.h>
#include <hip/hip_fp16.h>
#include <math.h>

#define NNODES 20000
#define NEDGES 320000
#define CIN 128
#define DOUT 64
#define NHEAD 4
#define HD 256            // NHEAD*DOUT
#define PROJW 320         // q(256) | skip(64)  -- f32 part
#define KVW 512           // k(256) | v(256)    -- fp16 part
#define NCOL 832          // total projection columns
#define NWAVES (1250 * 13)            // 16x64 output tiles
#define WPROJ_BLOCKS ((NWAVES + 3) / 4)      // 4063
#define SCATTER_BLOCKS ((NEDGES + 255) / 256)// 1250
#define PREP_TOTAL (NNODES * CIN / 8 + NCOL * CIN + NCOL)

typedef __attribute__((ext_vector_type(8))) _Float16 half8;
typedef __attribute__((ext_vector_type(4))) float f32x4;

// ---------------- fused prep (x->fp16, W^T fp16, bias) + edge histogram ------
__global__ __launch_bounds__(256) void prep_hist_kernel(
    const float* __restrict__ x,
    const float* __restrict__ Wq, const float* __restrict__ bq,
    const float* __restrict__ Wk, const float* __restrict__ bk,
    const float* __restrict__ Wv, const float* __restrict__ bv,
    const float* __restrict__ Ws, const float* __restrict__ bs,
    _Float16* __restrict__ xh, _Float16* __restrict__ Wth,
    float* __restrict__ bias832,
    const int* __restrict__ ei, int* __restrict__ deg)
{
    int i = blockIdx.x * 256 + threadIdx.x;
    if (i < NNODES * CIN / 8) {
        const float4* xv = reinterpret_cast<const float4*>(x);
        float4 u = xv[2 * i], v = xv[2 * i + 1];
        half8 h = { (_Float16)u.x, (_Float16)u.y, (_Float16)u.z, (_Float16)u.w,
                    (_Float16)v.x, (_Float16)v.y, (_Float16)v.z, (_Float16)v.w };
        *reinterpret_cast<half8*>(xh + (size_t)i * 8) = h;
        return;
    }
    i -= NNODES * CIN / 8;
    if (i < NCOL * CIN) {
        int c = i >> 7, k = i & 127;
        float v;
        if (c < 256)      v = Wq[k * HD + c];
        else if (c < 512) v = Wk[k * HD + (c - 256)];
        else if (c < 768) v = Wv[k * HD + (c - 512)];
        else              v = Ws[k * DOUT + (c - 768)];
        Wth[(size_t)c * CIN + k] = (_Float16)v;
        return;
    }
    i -= NCOL * CIN;
    if (i < NCOL) {
        float v;
        if (i < 256)      v = bq[i];
        else if (i < 512) v = bk[i - 256];
        else if (i < 768) v = bv[i - 512];
        else              v = bs[i - 768];
        bias832[i] = v;
        return;
    }
    i -= NCOL;
    if (i < NEDGES)
        atomicAdd(&deg[ei[NEDGES + i]], 1);
}

// ---------------- single-block prefix scan ----------------
__global__ __launch_bounds__(1024) void scan_kernel(
    const int* __restrict__ deg, int* __restrict__ rowptr, int* __restrict__ cursor)
{
    __shared__ int sd[1024];
    const int t = threadIdx.x;
    const int chunk = 20;                    // 1024*20 >= 20000
    const int base = t * chunk;
    int tsum = 0;
    for (int i = 0; i < chunk; ++i) {
        int idx = base + i;
        tsum += (idx < NNODES) ? deg[idx] : 0;
    }
    sd[t] = tsum; __syncthreads();
    for (int off = 1; off < 1024; off <<= 1) {
        int v = (t >= off) ? sd[t - off] : 0;
        __syncthreads();
        sd[t] += v;
        __syncthreads();
    }
    int run = sd[t] - tsum;                  // exclusive prefix
    for (int i = 0; i < chunk; ++i) {
        int idx = base + i;
        if (idx < NNODES) {
            int d = deg[idx];
            rowptr[idx] = run; cursor[idx] = run;
            run += d;
        }
    }
    if (t == 1023) rowptr[NNODES] = sd[1023];
}

// ---------------- fused: MFMA projection (blocks 0..4062) + CSR scatter ------
__global__ __launch_bounds__(256) void wproj_scatter_kernel(
    const _Float16* __restrict__ xh, const _Float16* __restrict__ Wth,
    const float* __restrict__ bias832,
    float* __restrict__ proj, __half* __restrict__ kvh,
    const int* __restrict__ ei, int* __restrict__ cursor, int* __restrict__ col)
{
    if (blockIdx.x >= WPROJ_BLOCKS) {
        int e = (blockIdx.x - WPROJ_BLOCKS) * 256 + threadIdx.x;
        if (e < NEDGES) {
            int src = ei[e];
            int dst = ei[NEDGES + e];
            int pos = atomicAdd(&cursor[dst], 1);
            col[pos] = src;
        }
        return;
    }
    const int wv = blockIdx.x * 4 + (threadIdx.x >> 6);
    if (wv >= NWAVES) return;
    const int l = threadIdx.x & 63;
    const int ct = wv / 1250, rt = wv % 1250;
    const int row0 = rt * 16, colb = ct * 64;
    const int lrow = l & 15, lk8 = (l >> 4) * 8;

    const _Float16* xr = xh + (size_t)(row0 + lrow) * CIN + lk8;
    const half8 a0 = *reinterpret_cast<const half8*>(xr);
    const half8 a1 = *reinterpret_cast<const half8*>(xr + 32);
    const half8 a2 = *reinterpret_cast<const half8*>(xr + 64);
    const half8 a3 = *reinterpret_cast<const half8*>(xr + 96);

    f32x4 acc[4];
    #pragma unroll
    for (int cg = 0; cg < 4; ++cg) {
        const _Float16* wr = Wth + (size_t)(colb + cg * 16 + lrow) * CIN + lk8;
        const half8 b0 = *reinterpret_cast<const half8*>(wr);
        const half8 b1 = *reinterpret_cast<const half8*>(wr + 32);
        const half8 b2 = *reinterpret_cast<const half8*>(wr + 64);
        const half8 b3 = *reinterpret_cast<const half8*>(wr + 96);
        f32x4 c = {0.f, 0.f, 0.f, 0.f};
        c = __builtin_amdgcn_mfma_f32_16x16x32_f16(a0, b0, c, 0, 0, 0);
        c = __builtin_amdgcn_mfma_f32_16x16x32_f16(a1, b1, c, 0, 0, 0);
        c = __builtin_amdgcn_mfma_f32_16x16x32_f16(a2, b2, c, 0, 0, 0);
        c = __builtin_amdgcn_mfma_f32_16x16x32_f16(a3, b3, c, 0, 0, 0);
        acc[cg] = c;
    }

    // D layout: col = lane&15, row = (lane>>4)*4 + reg  (m89-verified)
    const int orow = row0 + (l >> 4) * 4;
    #pragma unroll
    for (int cg = 0; cg < 4; ++cg) {
        const int c = colb + cg * 16 + lrow;      // global column 0..831
        const float bias = bias832[c];
        if (ct < 4) {                              // q -> f32 proj cols [0,256)
            #pragma unroll
            for (int r = 0; r < 4; ++r)
                proj[(size_t)(orow + r) * PROJW + c] = acc[cg][r] + bias;
        } else if (ct < 12) {                      // k/v -> fp16 kvh (col = c-256)
            #pragma unroll
            for (int r = 0; r < 4; ++r)
                kvh[(size_t)(orow + r) * KVW + (c - 256)] = __float2half(acc[cg][r] + bias);
        } else {                                   // skip -> f32 proj cols [256,320)
            #pragma unroll
            for (int r = 0; r < 4; ++r)
                proj[(size_t)(orow + r) * PROJW + (c - 512)] = acc[cg][r] + bias;
        }
    }
}

// ---------------- attention: 1 node/wave (max MLP) + fused BN partials -------
__global__ __launch_bounds__(256) void attn_bn_kernel(
    const float* __restrict__ proj, const __half* __restrict__ kvh,
    const int* __restrict__ rowptr, const int* __restrict__ col,
    float* __restrict__ out_pre, float* __restrict__ bnacc)
{
    const int wave = threadIdx.x >> 6;
    const int lane = threadIdx.x & 63;
    const int lane4 = lane * 4;
    const int node = blockIdx.x * 4 + wave;      // 5000*4 == NNODES exact

    const float4 q = *reinterpret_cast<const float4*>(proj + (size_t)node * PROJW + lane4);
    float m = -INFINITY, l = 0.f;
    float ax = 0.f, ay = 0.f, az = 0.f, aw = 0.f;
    int p = rowptr[node];
    const int pend = rowptr[node + 1];

    int j = (p < pend) ? col[p] : 0;
    const __half* bj = kvh + (size_t)j * KVW + lane4;
    uint2 kraw = *reinterpret_cast<const uint2*>(bj);
    uint2 vraw = *reinterpret_cast<const uint2*>(bj + 256);

    for (; p < pend; ++p) {
        const int p1 = p + 1;
        const int jn = (p1 < pend) ? col[p1] : j;
        const __half* bn = kvh + (size_t)jn * KVW + lane4;
        const uint2 krawn = *reinterpret_cast<const uint2*>(bn);
        const uint2 vrawn = *reinterpret_cast<const uint2*>(bn + 256);

        const float2 k0 = __half22float2(*reinterpret_cast<const __half2*>(&kraw.x));
        const float2 k1 = __half22float2(*reinterpret_cast<const __half2*>(&kraw.y));
        float partial = q.x * k0.x + q.y * k0.y + q.z * k1.x + q.w * k1.y;
        partial += __shfl_xor(partial, 1, 16);
        partial += __shfl_xor(partial, 2, 16);
        partial += __shfl_xor(partial, 4, 16);
        partial += __shfl_xor(partial, 8, 16);
        const float s = partial * 0.125f;           // /sqrt(64)
        const float mnew = fmaxf(m, s);
        const float scale = __expf(m - mnew);       // 0 on first edge (m=-inf)
        const float pc = __expf(s - mnew);
        const float2 v0 = __half22float2(*reinterpret_cast<const __half2*>(&vraw.x));
        const float2 v1 = __half22float2(*reinterpret_cast<const __half2*>(&vraw.y));
        l = l * scale + pc;
        ax = ax * scale + pc * v0.x;
        ay = ay * scale + pc * v0.y;
        az = az * scale + pc * v1.x;
        aw = aw * scale + pc * v1.y;
        m = mnew;
        kraw = krawn; vraw = vrawn;
    }
    const float inv = 1.f / (l + 1e-16f);
    float rx = ax * inv, ry = ay * inv, rz = az * inv, rw = aw * inv;
    rx += __shfl_xor(rx, 16); rx += __shfl_xor(rx, 32);
    ry += __shfl_xor(ry, 16); ry += __shfl_xor(ry, 32);
    rz += __shfl_xor(rz, 16); rz += __shfl_xor(rz, 32);
    rw += __shfl_xor(rw, 16); rw += __shfl_xor(rw, 32);

    float4 o = make_float4(0.f, 0.f, 0.f, 0.f);
    if (lane < 16) {
        const float4 sk = *reinterpret_cast<const float4*>(proj + (size_t)node * PROJW + 256 + lane4);
        o.x = rx * 0.25f + sk.x;
        o.y = ry * 0.25f + sk.y;
        o.z = rz * 0.25f + sk.z;
        o.w = rw * 0.25f + sk.w;
        *reinterpret_cast<float4*>(out_pre + (size_t)node * DOUT + lane4) = o;
    }

    // block-level BN partials: [s/ss][wave][channel] (one node per wave)
    __shared__ float sred[2][4][64];
    if (lane < 16) {
        sred[0][wave][lane4 + 0] = o.x;       sred[0][wave][lane4 + 1] = o.y;
        sred[0][wave][lane4 + 2] = o.z;       sred[0][wave][lane4 + 3] = o.w;
        sred[1][wave][lane4 + 0] = o.x * o.x; sred[1][wave][lane4 + 1] = o.y * o.y;
        sred[1][wave][lane4 + 2] = o.z * o.z; sred[1][wave][lane4 + 3] = o.w * o.w;
    }
    __syncthreads();
    if (threadIdx.x < 64) {
        const int c = threadIdx.x;
        float s  = sred[0][0][c] + sred[0][1][c] + sred[0][2][c] + sred[0][3][c];
        float ss = sred[1][0][c] + sred[1][1][c] + sred[1][2][c] + sred[1][3][c];
        atomicAdd(&bnacc[c], s);
        atomicAdd(&bnacc[64 + c], ss);
    }
}

// ---------------- BN finalize + GELU ----------------
__global__ __launch_bounds__(256) void final_kernel(
    const float* __restrict__ out_pre, const float* __restrict__ bnacc,
    const float* __restrict__ gamma, const float* __restrict__ beta,
    float* __restrict__ out)
{
    int idx = blockIdx.x * blockDim.x + threadIdx.x;
    if (idx >= NNODES * DOUT) return;
    const int c = idx & 63;
    const float mu = bnacc[c] * (1.f / NNODES);
    const float var = bnacc[64 + c] * (1.f / NNODES) - mu * mu;
    float v = (out_pre[idx] - mu) * rsqrtf(var + 1e-5f) * gamma[c] + beta[c];
    out[idx] = v * 0.5f * (1.f + erff(v * 0.70710678118654752f));
}

extern "C" void kernel_launch(void* const* d_in, const int* in_sizes, int n_in,
                              void* d_out, int out_size, void* d_ws, size_t ws_size,
                              hipStream_t stream) {
    const float* x     = (const float*)d_in[0];
    const int*   ei    = (const int*)d_in[1];
    const float* Wq    = (const float*)d_in[2];
    const float* bq    = (const float*)d_in[3];
    const float* Wk    = (const float*)d_in[4];
    const float* bk    = (const float*)d_in[5];
    const float* Wv    = (const float*)d_in[6];
    const float* bv    = (const float*)d_in[7];
    const float* Wskip = (const float*)d_in[8];
    const float* bskip = (const float*)d_in[9];
    const float* gamma = (const float*)d_in[10];
    const float* beta  = (const float*)d_in[11];
    float* out = (float*)d_out;

    // workspace layout (all 16B-aligned)
    __half*   kvh    = (__half*)d_ws;                          // N*512 fp16 = 20,480,000 B
    _Float16* xh     = (_Float16*)((char*)d_ws + 20480000);    // N*128 fp16 =  5,120,000 B
    _Float16* Wth    = xh + (size_t)NNODES * CIN;              // 832*128 fp16 = 212,992 B
    float*    bias832= (float*)(Wth + (size_t)NCOL * CIN);     // 832 f32 = 3,328 B
    float*    proj   = bias832 + NCOL;                         // N*320 f32 = 25,600,000 B
    float*    out_pre= proj + (size_t)NNODES * PROJW;          // N*64 f32
    float*    bnacc  = out_pre + (size_t)NNODES * DOUT;        // 128 f32
    int*      deg    = (int*)(bnacc + 128);                    // N
    int*      rowptr = deg + NNODES;                           // N+1
    int*      cursor = rowptr + NNODES + 1;                    // N
    int*      col    = cursor + NNODES;                        // E

    hipMemsetAsync(bnacc, 0, (128 + NNODES) * sizeof(int), stream);

    const int ph_total = PREP_TOTAL + NEDGES;
    prep_hist_kernel<<<(ph_total + 255) / 256, 256, 0, stream>>>(
        x, Wq, bq, Wk, bk, Wv, bv, Wskip, bskip, xh, Wth, bias832, ei, deg);
    scan_kernel<<<1, 1024, 0, stream>>>(deg, rowptr, cursor);
    wproj_scatter_kernel<<<WPROJ_BLOCKS + SCATTER_BLOCKS, 256, 0, stream>>>(
        xh, Wth, bias832, proj, kvh, ei, cursor, col);
    attn_bn_kernel<<<NNODES / 4, 256, 0, stream>>>(proj, kvh, rowptr, col, out_pre, bnacc);
    final_kernel<<<(NNODES * DOUT + 255) / 256, 256, 0, stream>>>(
        out_pre, bnacc, gamma, beta, out);
}

// Round 18
// 255.420 us; speedup vs baseline: 1.2974x; 1.2974x over previous
//
#include <hip/hip_runtime.h>
#include <hip/hip_fp16.h>
#include <math.h>

#define NNODES 20000
#define NEDGES 320000
#define CIN 128
#define DOUT 64
#define NHEAD 4
#define HD 256            // NHEAD*DOUT
#define PROJW 320         // q(256) | skip(64)  -- f32 part
#define KVW 512           // k(256) | v(256)    -- fp16 part
#define NCOL 832          // total projection columns
#define NWAVES (1250 * 13)            // 16x64 output tiles
#define WPROJ_BLOCKS ((NWAVES + 3) / 4)      // 4063
#define SCATTER_BLOCKS ((NEDGES + 255) / 256)// 1250
#define PREP_TOTAL (NNODES * CIN / 8 + NCOL * CIN + NCOL)

typedef __attribute__((ext_vector_type(8))) _Float16 half8;
typedef __attribute__((ext_vector_type(4))) float f32x4;

// ---------------- fused prep (x->fp16, W^T fp16, bias) + edge histogram ------
__global__ __launch_bounds__(256) void prep_hist_kernel(
    const float* __restrict__ x,
    const float* __restrict__ Wq, const float* __restrict__ bq,
    const float* __restrict__ Wk, const float* __restrict__ bk,
    const float* __restrict__ Wv, const float* __restrict__ bv,
    const float* __restrict__ Ws, const float* __restrict__ bs,
    _Float16* __restrict__ xh, _Float16* __restrict__ Wth,
    float* __restrict__ bias832,
    const int* __restrict__ ei, int* __restrict__ deg)
{
    int i = blockIdx.x * 256 + threadIdx.x;
    if (i < NNODES * CIN / 8) {
        const float4* xv = reinterpret_cast<const float4*>(x);
        float4 u = xv[2 * i], v = xv[2 * i + 1];
        half8 h = { (_Float16)u.x, (_Float16)u.y, (_Float16)u.z, (_Float16)u.w,
                    (_Float16)v.x, (_Float16)v.y, (_Float16)v.z, (_Float16)v.w };
        *reinterpret_cast<half8*>(xh + (size_t)i * 8) = h;
        return;
    }
    i -= NNODES * CIN / 8;
    if (i < NCOL * CIN) {
        int c = i >> 7, k = i & 127;
        float v;
        if (c < 256)      v = Wq[k * HD + c];
        else if (c < 512) v = Wk[k * HD + (c - 256)];
        else if (c < 768) v = Wv[k * HD + (c - 512)];
        else              v = Ws[k * DOUT + (c - 768)];
        Wth[(size_t)c * CIN + k] = (_Float16)v;
        return;
    }
    i -= NCOL * CIN;
    if (i < NCOL) {
        float v;
        if (i < 256)      v = bq[i];
        else if (i < 512) v = bk[i - 256];
        else if (i < 768) v = bv[i - 512];
        else              v = bs[i - 768];
        bias832[i] = v;
        return;
    }
    i -= NCOL;
    if (i < NEDGES)
        atomicAdd(&deg[ei[NEDGES + i]], 1);
}

// ---------------- single-block prefix scan ----------------
__global__ __launch_bounds__(1024) void scan_kernel(
    const int* __restrict__ deg, int* __restrict__ rowptr, int* __restrict__ cursor)
{
    __shared__ int sd[1024];
    const int t = threadIdx.x;
    const int chunk = 20;                    // 1024*20 >= 20000
    const int base = t * chunk;
    int tsum = 0;
    for (int i = 0; i < chunk; ++i) {
        int idx = base + i;
        tsum += (idx < NNODES) ? deg[idx] : 0;
    }
    sd[t] = tsum; __syncthreads();
    for (int off = 1; off < 1024; off <<= 1) {
        int v = (t >= off) ? sd[t - off] : 0;
        __syncthreads();
        sd[t] += v;
        __syncthreads();
    }
    int run = sd[t] - tsum;                  // exclusive prefix
    for (int i = 0; i < chunk; ++i) {
        int idx = base + i;
        if (idx < NNODES) {
            int d = deg[idx];
            rowptr[idx] = run; cursor[idx] = run;
            run += d;
        }
    }
    if (t == 1023) rowptr[NNODES] = sd[1023];
}

// ---------------- fused: MFMA projection (blocks 0..4062) + CSR scatter ------
__global__ __launch_bounds__(256) void wproj_scatter_kernel(
    const _Float16* __restrict__ xh, const _Float16* __restrict__ Wth,
    const float* __restrict__ bias832,
    float* __restrict__ proj, __half* __restrict__ kvh,
    const int* __restrict__ ei, int* __restrict__ cursor, int* __restrict__ col)
{
    if (blockIdx.x >= WPROJ_BLOCKS) {
        int e = (blockIdx.x - WPROJ_BLOCKS) * 256 + threadIdx.x;
        if (e < NEDGES) {
            int src = ei[e];
            int dst = ei[NEDGES + e];
            int pos = atomicAdd(&cursor[dst], 1);
            col[pos] = src;
        }
        return;
    }
    const int wv = blockIdx.x * 4 + (threadIdx.x >> 6);
    if (wv >= NWAVES) return;
    const int l = threadIdx.x & 63;
    const int ct = wv / 1250, rt = wv % 1250;
    const int row0 = rt * 16, colb = ct * 64;
    const int lrow = l & 15, lk8 = (l >> 4) * 8;

    const _Float16* xr = xh + (size_t)(row0 + lrow) * CIN + lk8;
    const half8 a0 = *reinterpret_cast<const half8*>(xr);
    const half8 a1 = *reinterpret_cast<const half8*>(xr + 32);
    const half8 a2 = *reinterpret_cast<const half8*>(xr + 64);
    const half8 a3 = *reinterpret_cast<const half8*>(xr + 96);

    f32x4 acc[4];
    #pragma unroll
    for (int cg = 0; cg < 4; ++cg) {
        const _Float16* wr = Wth + (size_t)(colb + cg * 16 + lrow) * CIN + lk8;
        const half8 b0 = *reinterpret_cast<const half8*>(wr);
        const half8 b1 = *reinterpret_cast<const half8*>(wr + 32);
        const half8 b2 = *reinterpret_cast<const half8*>(wr + 64);
        const half8 b3 = *reinterpret_cast<const half8*>(wr + 96);
        f32x4 c = {0.f, 0.f, 0.f, 0.f};
        c = __builtin_amdgcn_mfma_f32_16x16x32_f16(a0, b0, c, 0, 0, 0);
        c = __builtin_amdgcn_mfma_f32_16x16x32_f16(a1, b1, c, 0, 0, 0);
        c = __builtin_amdgcn_mfma_f32_16x16x32_f16(a2, b2, c, 0, 0, 0);
        c = __builtin_amdgcn_mfma_f32_16x16x32_f16(a3, b3, c, 0, 0, 0);
        acc[cg] = c;
    }

    // D layout: col = lane&15, row = (lane>>4)*4 + reg  (m89-verified)
    const int orow = row0 + (l >> 4) * 4;
    #pragma unroll
    for (int cg = 0; cg < 4; ++cg) {
        const int c = colb + cg * 16 + lrow;      // global column 0..831
        const float bias = bias832[c];
        if (ct < 4) {                              // q -> f32 proj cols [0,256)
            #pragma unroll
            for (int r = 0; r < 4; ++r)
                proj[(size_t)(orow + r) * PROJW + c] = acc[cg][r] + bias;
        } else if (ct < 12) {                      // k/v -> fp16 kvh (col = c-256)
            #pragma unroll
            for (int r = 0; r < 4; ++r)
                kvh[(size_t)(orow + r) * KVW + (c - 256)] = __float2half(acc[cg][r] + bias);
        } else {                                   // skip -> f32 proj cols [256,320)
            #pragma unroll
            for (int r = 0; r < 4; ++r)
                proj[(size_t)(orow + r) * PROJW + (c - 512)] = acc[cg][r] + bias;
        }
    }
}

// ---------------- per-node attention (1 wave/node, no atomics, no LDS) -------
__global__ __launch_bounds__(256) void attn_kernel(
    const float* __restrict__ proj, const __half* __restrict__ kvh,
    const int* __restrict__ rowptr, const int* __restrict__ col,
    float* __restrict__ out_pre)
{
    const int node = blockIdx.x * 4 + (threadIdx.x >> 6);
    const int lane = threadIdx.x & 63;
    const int lane4 = lane * 4;

    const float4 q = *reinterpret_cast<const float4*>(proj + (size_t)node * PROJW + lane4);

    float m = -INFINITY, l = 0.f;
    float ax = 0.f, ay = 0.f, az = 0.f, aw = 0.f;
    int p = rowptr[node];
    const int pend = rowptr[node + 1];

    int j = (p < pend) ? col[p] : 0;
    const __half* bj = kvh + (size_t)j * KVW + lane4;
    uint2 kraw = *reinterpret_cast<const uint2*>(bj);
    uint2 vraw = *reinterpret_cast<const uint2*>(bj + 256);

    for (; p < pend; ++p) {
        const int p1 = p + 1;
        const int jn = (p1 < pend) ? col[p1] : j;
        const __half* bn = kvh + (size_t)jn * KVW + lane4;
        const uint2 krawn = *reinterpret_cast<const uint2*>(bn);
        const uint2 vrawn = *reinterpret_cast<const uint2*>(bn + 256);

        const float2 k0 = __half22float2(*reinterpret_cast<const __half2*>(&kraw.x));
        const float2 k1 = __half22float2(*reinterpret_cast<const __half2*>(&kraw.y));
        float partial = q.x * k0.x + q.y * k0.y + q.z * k1.x + q.w * k1.y;
        partial += __shfl_xor(partial, 1, 16);
        partial += __shfl_xor(partial, 2, 16);
        partial += __shfl_xor(partial, 4, 16);
        partial += __shfl_xor(partial, 8, 16);
        const float s = partial * 0.125f;           // /sqrt(64)
        const float mnew = fmaxf(m, s);
        const float scale = __expf(m - mnew);       // 0 on first edge (m=-inf)
        const float pc = __expf(s - mnew);
        const float2 v0 = __half22float2(*reinterpret_cast<const __half2*>(&vraw.x));
        const float2 v1 = __half22float2(*reinterpret_cast<const __half2*>(&vraw.y));
        l = l * scale + pc;
        ax = ax * scale + pc * v0.x;
        ay = ay * scale + pc * v0.y;
        az = az * scale + pc * v1.x;
        aw = aw * scale + pc * v1.y;
        m = mnew;
        kraw = krawn; vraw = vrawn;
    }
    const float inv = 1.f / (l + 1e-16f);
    float rx = ax * inv, ry = ay * inv, rz = az * inv, rw = aw * inv;
    rx += __shfl_xor(rx, 16); rx += __shfl_xor(rx, 32);
    ry += __shfl_xor(ry, 16); ry += __shfl_xor(ry, 32);
    rz += __shfl_xor(rz, 16); rz += __shfl_xor(rz, 32);
    rw += __shfl_xor(rw, 16); rw += __shfl_xor(rw, 32);
    if (lane < 16) {
        const float4 sk = *reinterpret_cast<const float4*>(proj + (size_t)node * PROJW + 256 + lane4);
        float4 o;
        o.x = rx * 0.25f + sk.x;
        o.y = ry * 0.25f + sk.y;
        o.z = rz * 0.25f + sk.z;
        o.w = rw * 0.25f + sk.w;
        *reinterpret_cast<float4*>(out_pre + (size_t)node * DOUT + lane4) = o;
    }
}

// ---------------- BatchNorm reduce (128 blocks -> low atomic contention) -----
__global__ __launch_bounds__(256) void bnred_kernel(
    const float* __restrict__ out_pre, float* __restrict__ bnacc)
{
    const int tid = threadIdx.x;
    const int c = tid & 63, g = tid >> 6;
    float s = 0.f, ss = 0.f;
    for (int r = blockIdx.x * 4 + g; r < NNODES; r += gridDim.x * 4) {
        float v = out_pre[(size_t)r * DOUT + c];
        s += v; ss += v * v;
    }
    __shared__ float sd[256];
    sd[tid] = s; __syncthreads();
    float s4 = 0.f;
    if (g == 0) s4 = sd[tid] + sd[tid + 64] + sd[tid + 128] + sd[tid + 192];
    __syncthreads();
    sd[tid] = ss; __syncthreads();
    if (g == 0) {
        float ss4 = sd[tid] + sd[tid + 64] + sd[tid + 128] + sd[tid + 192];
        atomicAdd(&bnacc[c], s4);
        atomicAdd(&bnacc[64 + c], ss4);
    }
}

// ---------------- BN finalize + GELU ----------------
__global__ __launch_bounds__(256) void final_kernel(
    const float* __restrict__ out_pre, const float* __restrict__ bnacc,
    const float* __restrict__ gamma, const float* __restrict__ beta,
    float* __restrict__ out)
{
    int idx = blockIdx.x * blockDim.x + threadIdx.x;
    if (idx >= NNODES * DOUT) return;
    const int c = idx & 63;
    const float mu = bnacc[c] * (1.f / NNODES);
    const float var = bnacc[64 + c] * (1.f / NNODES) - mu * mu;
    float v = (out_pre[idx] - mu) * rsqrtf(var + 1e-5f) * gamma[c] + beta[c];
    out[idx] = v * 0.5f * (1.f + erff(v * 0.70710678118654752f));
}

extern "C" void kernel_launch(void* const* d_in, const int* in_sizes, int n_in,
                              void* d_out, int out_size, void* d_ws, size_t ws_size,
                              hipStream_t stream) {
    const float* x     = (const float*)d_in[0];
    const int*   ei    = (const int*)d_in[1];
    const float* Wq    = (const float*)d_in[2];
    const float* bq    = (const float*)d_in[3];
    const float* Wk    = (const float*)d_in[4];
    const float* bk    = (const float*)d_in[5];
    const float* Wv    = (const float*)d_in[6];
    const float* bv    = (const float*)d_in[7];
    const float* Wskip = (const float*)d_in[8];
    const float* bskip = (const float*)d_in[9];
    const float* gamma = (const float*)d_in[10];
    const float* beta  = (const float*)d_in[11];
    float* out = (float*)d_out;

    // workspace layout (all 16B-aligned)
    __half*   kvh    = (__half*)d_ws;                          // N*512 fp16 = 20,480,000 B
    _Float16* xh     = (_Float16*)((char*)d_ws + 20480000);    // N*128 fp16 =  5,120,000 B
    _Float16* Wth    = xh + (size_t)NNODES * CIN;              // 832*128 fp16 = 212,992 B
    float*    bias832= (float*)(Wth + (size_t)NCOL * CIN);     // 832 f32 = 3,328 B
    float*    proj   = bias832 + NCOL;                         // N*320 f32 = 25,600,000 B
    float*    out_pre= proj + (size_t)NNODES * PROJW;          // N*64 f32
    float*    bnacc  = out_pre + (size_t)NNODES * DOUT;        // 128 f32
    int*      deg    = (int*)(bnacc + 128);                    // N
    int*      rowptr = deg + NNODES;                           // N+1
    int*      cursor = rowptr + NNODES + 1;                    // N
    int*      col    = cursor + NNODES;                        // E

    hipMemsetAsync(bnacc, 0, (128 + NNODES) * sizeof(int), stream);

    const int ph_total = PREP_TOTAL + NEDGES;
    prep_hist_kernel<<<(ph_total + 255) / 256, 256, 0, stream>>>(
        x, Wq, bq, Wk, bk, Wv, bv, Wskip, bskip, xh, Wth, bias832, ei, deg);
    scan_kernel<<<1, 1024, 0, stream>>>(deg, rowptr, cursor);
    wproj_scatter_kernel<<<WPROJ_BLOCKS + SCATTER_BLOCKS, 256, 0, stream>>>(
        xh, Wth, bias832, proj, kvh, ei, cursor, col);
    attn_kernel<<<NNODES / 4, 256, 0, stream>>>(proj, kvh, rowptr, col, out_pre);
    bnred_kernel<<<128, 256, 0, stream>>>(out_pre, bnacc);
    final_kernel<<<(NNODES * DOUT + 255) / 256, 256, 0, stream>>>(
        out_pre, bnacc, gamma, beta, out);
}